// Round 5
// baseline (353.832 us; speedup 1.0000x reference)
//
#include <hip/hip_runtime.h>

#define L_IN     4000
#define CIN      512
#define KSZ      16
#define LOUT     31992   // 8 * 3999
#define NQ       3999    // valid q: 0..3998
#define CCH      32      // ci rows per block (16 ci-chunks)
#define NST      8       // stages per block
#define RPS      4       // full rows staged per stage (62.5 KB)
#define LOUT_PAD 32768   // per-partial slice; pad swallows invalid q
#define NCH      16      // ci-chunks = partials per output
#define WS_FLOATS ((size_t)NCH * 16 * LOUT_PAD)   // 33.6 MB workspace

// ---------------------------------------------------------------------------
// Stage kernel: grid (16 ci-chunks, 16 b) = 256 blocks of 1024 threads,
// 1 block/CU (LDS-bound: 127 KB).
// DECISIVE RUN-LENGTH TEST: block owns 32 ci rows x ALL 4000 q = one fully
// CONTIGUOUS 512 KB span of x. It stages 4 FULL rows (62.5 KB) per stage
// into double-buffered LDS; the per-stage __syncthreads() keeps all 16
// waves' loads inside one sliding 64 KB window -> long sequential runs
// with TEMPORAL coherence (what R3's barrier-free macro-contiguity lacked:
// wave drift scrambled the address stream back to 1 KB chunks).
// Compute reads x from LDS (per-lane contiguous b128, conflict-free;
// scalar halo), so the HBM pattern is fully decoupled from the compute
// pattern. T14 split: next stage's global loads issue BEFORE compute,
// vmcnt + ds_write after (HBM latency hides under the FMA burst).
// Multiplicity 16 over ci-chunks -> R3's proven workspace partials +
// reduce kernel (no atomics, no memset; invalid q lands in slice pad).
// ---------------------------------------------------------------------------
__global__ __launch_bounds__(1024, 4)
void dereverb_stage(const float* __restrict__ x,
                    const float* __restrict__ t60s,
                    const float* __restrict__ kw,
                    float* __restrict__ ws)
{
    __shared__ float xbuf[2 * RPS * L_IN];   // 125 KB (two 4-row buffers)
    __shared__ float wlds[CCH * KSZ];        // 2 KB

    const int cx  = blockIdx.x;
    const int b   = blockIdx.y;
    const int tid = threadIdx.x;

    // Per-sample kernel index (uniform): jnp.round = RNE = rintf.
    float t60 = t60s[b & 7];
    int kidx = (int)rintf(t60 * 100.0f) - 10;
    kidx = __builtin_amdgcn_readfirstlane(kidx);

    // Stage this chunk's 32x16 weights (2 KB): 128 float4 by threads 0..127.
    if (tid < 128)
        ((float4*)wlds)[tid] =
            ((const float4*)(kw + ((size_t)kidx * CIN + cx * CCH) * KSZ))[tid];

    // Block's x-region: 32 contiguous rows = 512 KB contiguous.
    const float4* src = (const float4*)(x + ((size_t)b * CIN + cx * CCH) * L_IN);

    // Prologue: stage 0 -> buf 0 (4000 float4s, block-linear, coalesced).
    {
        float4 p0 = src[tid];
        float4 p1 = src[tid + 1024];
        float4 p2 = src[tid + 2048];
        float4 p3 = {};
        if (tid < 928) p3 = src[tid + 3072];
        ((float4*)xbuf)[tid]        = p0;
        ((float4*)xbuf)[tid + 1024] = p1;
        ((float4*)xbuf)[tid + 2048] = p2;
        if (tid < 928) ((float4*)xbuf)[tid + 3072] = p3;
    }
    __syncthreads();

    // Thread's q window [qb, qb+4); clamped LDS reads for tail threads
    // (their garbage lands in the slice pad at the ws store).
    const int qb  = 4 * tid;                        // 0..4092
    const int qbl = qb < 3996 ? qb : 3996;          // float4 base within row
    const int qhl = (qb + 4) < NQ ? (qb + 4) : NQ;  // halo x[q+4]

    float acc[4][8];
    #pragma unroll
    for (int qi = 0; qi < 4; ++qi)
        #pragma unroll
        for (int r = 0; r < 8; ++r) acc[qi][r] = 0.0f;

#define FMA_BODY(A, AN, W0, W1, W2, W3) do {                        \
        const float xl[4] = {(A).x, (A).y, (A).z, (A).w};           \
        const float xh[4] = {(A).y, (A).z, (A).w, (AN)};            \
        const float wa[8] = {(W0).x,(W0).y,(W0).z,(W0).w,           \
                             (W1).x,(W1).y,(W1).z,(W1).w};          \
        const float wb[8] = {(W2).x,(W2).y,(W2).z,(W2).w,           \
                             (W3).x,(W3).y,(W3).z,(W3).w};          \
        _Pragma("unroll")                                           \
        for (int qi = 0; qi < 4; ++qi)                              \
            _Pragma("unroll")                                       \
            for (int r = 0; r < 8; ++r) {                           \
                acc[qi][r] = fmaf(xh[qi], wa[r], acc[qi][r]);       \
                acc[qi][r] = fmaf(xl[qi], wb[r], acc[qi][r]);       \
            }                                                       \
    } while (0)

    #pragma unroll 2
    for (int s = 0; s < NST; ++s) {
        // T14 issue-early: next stage's global loads (non-blocking).
        float4 p0, p1, p2, p3 = {};
        if (s < NST - 1) {
            const float4* sp = src + (size_t)(s + 1) * (RPS * L_IN / 4);
            p0 = sp[tid];
            p1 = sp[tid + 1024];
            p2 = sp[tid + 2048];
            if (tid < 928) p3 = sp[tid + 3072];
        }

        // Compute the current stage's 4 rows from LDS.
        const float* bufc = xbuf + (s & 1) * (RPS * L_IN);
        #pragma unroll
        for (int r = 0; r < RPS; ++r) {
            const float* row = bufc + r * L_IN;
            float4 a = *(const float4*)(row + qbl);
            float  h = row[qhl];
            const float4* wr = (const float4*)(wlds + (s * RPS + r) * KSZ);
            float4 w0 = wr[0], w1 = wr[1], w2 = wr[2], w3 = wr[3];
            FMA_BODY(a, h, w0, w1, w2, w3);
        }

        // Write-late: drain loads (compiler vmcnt) + ds_write next buffer.
        if (s < NST - 1) {
            float* bufn = xbuf + ((s + 1) & 1) * (RPS * L_IN);
            ((float4*)bufn)[tid]        = p0;
            ((float4*)bufn)[tid + 1024] = p1;
            ((float4*)bufn)[tid + 2048] = p2;
            if (tid < 928) ((float4*)bufn)[tid + 3072] = p3;
        }
        __syncthreads();
    }

    // Epilogue: coalesced partial store. Thread's 32 consecutive floats
    // start at 8*qb; invalid q (>3998, incl. tail threads) lands in the
    // slice pad [31992, 32768) which the reduce kernel never reads.
    float* op = ws + (size_t)(cx * 16 + b) * LOUT_PAD + (size_t)8 * qb;
    #pragma unroll
    for (int qi = 0; qi < 4; ++qi) {
        float4 lo = {acc[qi][0], acc[qi][1], acc[qi][2], acc[qi][3]};
        float4 hi = {acc[qi][4], acc[qi][5], acc[qi][6], acc[qi][7]};
        ((float4*)(op + 8 * qi))[0] = lo;
        ((float4*)(op + 8 * qi))[1] = hi;
    }
#undef FMA_BODY
}

// ---------------------------------------------------------------------------
// Reduce kernel (R3-proven): out[b][t] = sum_c ws[c*16+b][t].
// Grid (32, 16) x 256 threads; 16 coalesced float4 addends per thread.
// ---------------------------------------------------------------------------
__global__ __launch_bounds__(256, 8)
void dereverb_reduce(const float* __restrict__ ws, float* __restrict__ out)
{
    const int b  = blockIdx.y;
    const int t4 = blockIdx.x * 256 + threadIdx.x;
    if (t4 >= LOUT / 4) return;

    const float4* p = (const float4*)(ws + (size_t)b * LOUT_PAD) + t4;
    float4 s = {0.0f, 0.0f, 0.0f, 0.0f};
    #pragma unroll
    for (int c = 0; c < NCH; ++c) {
        float4 v = *p;
        s.x += v.x; s.y += v.y; s.z += v.z; s.w += v.w;
        p += (size_t)16 * LOUT_PAD / 4;
    }
    ((float4*)(out + (size_t)b * LOUT))[t4] = s;
}

// ---------------------------------------------------------------------------
// Fallback (ws too small): R0 single-kernel, 195 us known-good.
// ---------------------------------------------------------------------------
#define QPB 256
#define RST 1088
__global__ __launch_bounds__(1024, 4)
void dereverb_fallback(const float* __restrict__ x,
                       const float* __restrict__ t60s,
                       const float* __restrict__ kw,
                       float* __restrict__ out)
{
    __shared__ float lds[8 * RST];

    const int b    = blockIdx.y;
    const int q0   = blockIdx.x * QPB;
    const int tid  = threadIdx.x;
    const int lane = tid & 63;
    const int wave = tid >> 6;

    float t60 = t60s[b & 7];
    int kidx = (int)rintf(t60 * 100.0f) - 10;
    kidx = __builtin_amdgcn_readfirstlane(kidx);
    const float4* wsrc = (const float4*)(kw + (size_t)kidx * (CIN * KSZ));

    ((float4*)lds)[tid]        = wsrc[tid];
    ((float4*)lds)[tid + 1024] = wsrc[tid + 1024];
    __syncthreads();

    const int qb  = q0 + 4 * lane;
    const int qbl = qb < 3996 ? qb : 3996;
    const int qan = (qb + 4) < NQ ? (qb + 4) : NQ;

    const float* xr = x + ((size_t)b * CIN + wave * 32) * L_IN;
    const float* xp = xr + qbl;
    const float* xq = xr + qan;
    const float4* wl = (const float4*)(lds + wave * 32 * KSZ);

    float acc[4][8];
    #pragma unroll
    for (int qi = 0; qi < 4; ++qi)
        #pragma unroll
        for (int r = 0; r < 8; ++r) acc[qi][r] = 0.0f;

    #pragma unroll 4
    for (int ci = 0; ci < 32; ++ci) {
        float4 a  = *(const float4*)xp;
        float  an = *xq;
        xp += L_IN;
        xq += L_IN;

        float4 wv[4];
        wv[0] = wl[0]; wv[1] = wl[1]; wv[2] = wl[2]; wv[3] = wl[3];
        wl += 4;
        const float* wf = (const float*)wv;

        const float x0v[4] = {a.x, a.y, a.z, a.w};
        const float x1v[4] = {a.y, a.z, a.w, an};
        #pragma unroll
        for (int qi = 0; qi < 4; ++qi)
            #pragma unroll
            for (int r = 0; r < 8; ++r) {
                acc[qi][r] = fmaf(x1v[qi], wf[r],     acc[qi][r]);
                acc[qi][r] = fmaf(x0v[qi], wf[r + 8], acc[qi][r]);
            }
    }

    #pragma unroll
    for (int qi = 0; qi < 4; ++qi)
        if (qb + qi > NQ - 1)
            #pragma unroll
            for (int r = 0; r < 8; ++r) acc[qi][r] = 0.0f;

    const size_t obase = (size_t)b * LOUT + (size_t)q0 * 8;
    #pragma unroll
    for (int p = 0; p < 2; ++p) {
        __syncthreads();
        if (wave >= 8) {
            float* rp = lds + (wave - 8) * RST + lane * 17;
            #pragma unroll
            for (int qih = 0; qih < 2; ++qih)
                #pragma unroll
                for (int r = 0; r < 8; ++r)
                    rp[qih * 8 + r] = acc[2 * p + qih][r];
        }
        __syncthreads();
        if (wave < 8) {
            float* rp = lds + wave * RST + lane * 17;
            #pragma unroll
            for (int qih = 0; qih < 2; ++qih)
                #pragma unroll
                for (int r = 0; r < 8; ++r)
                    rp[qih * 8 + r] += acc[2 * p + qih][r];
        }
        __syncthreads();
        int k = tid >> 4, j = tid & 15;
        int tl = 32 * k + 16 * p + j;
        if (q0 * 8 + tl < LOUT) {
            float s = 0.0f;
            #pragma unroll
            for (int w = 0; w < 8; ++w)
                s += lds[w * RST + k * 17 + j];
            out[obase + tl] = s;
        }
    }
}

extern "C" void kernel_launch(void* const* d_in, const int* in_sizes, int n_in,
                              void* d_out, int out_size, void* d_ws, size_t ws_size,
                              hipStream_t stream) {
    const float* x    = (const float*)d_in[0];   // (16, 512, 4000)
    const float* t60s = (const float*)d_in[1];   // (8,)
    const float* kw   = (const float*)d_in[2];   // (41, 512, 1, 16)
    float* out = (float*)d_out;                  // (16, 1, 31992)

    if (ws_size >= WS_FLOATS * sizeof(float) && d_ws != nullptr) {
        float* ws = (float*)d_ws;
        dim3 g1(NCH, 16);                        // (16 ci-chunks, 16 b) = 256
        dereverb_stage<<<g1, 1024, 0, stream>>>(x, t60s, kw, ws);
        dim3 g2((LOUT / 4 + 255) / 256, 16);     // (32, 16) = 512
        dereverb_reduce<<<g2, 256, 0, stream>>>(ws, out);
    } else {
        dim3 grid((NQ + QPB - 1) / QPB, 16);     // (16, 16)
        dereverb_fallback<<<grid, 1024, 0, stream>>>(x, t60s, kw, out);
    }
}

// Round 6
// 206.359 us; speedup vs baseline: 1.7146x; 1.7146x over previous
//
#include <hip/hip_runtime.h>

#define L_IN     4000
#define CIN      512
#define KSZ      16
#define LOUT     31992   // 8 * 3999
#define NQ       3999    // valid q: 0..3998
#define CCH      32      // ci rows per block (16 ci-chunks)
#define NST      8       // stages per block
#define RPS      4       // full rows staged per stage (62.5 KB)
#define LOUT_PAD 32768   // per-partial slice; pad swallows invalid q
#define NCH      16      // ci-chunks = partials per output
#define WS_FLOATS ((size_t)NCH * 16 * LOUT_PAD)   // 33.6 MB workspace

// Async global->LDS, width 16 (guide m97): LDS dest is wave-uniform base +
// lane*16, which our linear layout satisfies exactly. Exec-masked lanes skip.
#define GLOAD16(gp, lp)                                                     \
    __builtin_amdgcn_global_load_lds(                                       \
        (const __attribute__((address_space(1))) void*)(gp),                \
        (__attribute__((address_space(3))) void*)(lp), 16, 0, 0)

// ---------------------------------------------------------------------------
// Stage kernel: grid (16 ci-chunks, 16 b) = 256 blocks of 1024 threads,
// 1 block/CU (LDS 127 KB). Block owns 32 ci rows x ALL 4000 q = one fully
// CONTIGUOUS 512 KB span of x, staged 4 rows (62.5 KB) at a time into
// double-buffered LDS. The per-stage __syncthreads keeps all 16 waves'
// loads inside one sliding 64 KB window -> long, temporally-coherent
// sequential runs (the run-length test R5 meant to run).
// R5 invalidators fixed: (1) __launch_bounds__(1024) only -> VGPR cap 128,
// no scratch (R5: 64-cap forced ~660 MB of spill traffic); (2) staging via
// global_load_lds -> zero staging VGPRs + async issue-early for free;
// (3) halo read as a second lane-contiguous float4 (+16 B) instead of the
// stride-16B scalar ds_read (R5's 762K 8-way bank conflicts).
// Multiplicity 16 over ci-chunks -> R3-proven workspace partials + reduce
// (no atomics, no memset; invalid q lands in the slice pad).
// ---------------------------------------------------------------------------
__global__ __launch_bounds__(1024)
void dereverb_stage(const float* __restrict__ x,
                    const float* __restrict__ t60s,
                    const float* __restrict__ kw,
                    float* __restrict__ ws)
{
    __shared__ float xbuf[2 * RPS * L_IN];   // 125 KB (two 4-row buffers)
    __shared__ float wlds[CCH * KSZ];        // 2 KB

    const int cx   = blockIdx.x;
    const int b    = blockIdx.y;
    const int tid  = threadIdx.x;
    const int wave = tid >> 6;

    // Per-sample kernel index (uniform): jnp.round = RNE = rintf.
    float t60 = t60s[b & 7];
    int kidx = (int)rintf(t60 * 100.0f) - 10;
    kidx = __builtin_amdgcn_readfirstlane(kidx);

    // Stage this chunk's 32x16 weights (2 KB): 128 float4 by threads 0..127.
    if (tid < 128)
        ((float4*)wlds)[tid] =
            ((const float4*)(kw + ((size_t)kidx * CIN + cx * CCH) * KSZ))[tid];

    // Block's x-region: 32 contiguous rows = 512 KB contiguous.
    const float4* src = (const float4*)(x + ((size_t)b * CIN + cx * CCH) * L_IN);

    // Async stage s -> buffer (s&1). 4000 float4/stage, 4 issues/thread;
    // only k=3 needs the tail guard (3072+tid < 4000 <=> tid < 928).
    // LDS dest per wave: float4 slot k*1024 + wave*64 (+lane, implicit).
#define STAGE(s_, buf_) do {                                                \
        const float4* sp_ = src + (size_t)(s_) * (RPS * L_IN / 4);          \
        float* nb_ = xbuf + (buf_) * (RPS * L_IN);                          \
        _Pragma("unroll")                                                   \
        for (int k = 0; k < 4; ++k) {                                       \
            const int slot = k * 1024 + tid;                                \
            if (slot < RPS * L_IN / 4)                                      \
                GLOAD16(sp_ + slot, nb_ + 4 * (k * 1024 + wave * 64));      \
        }                                                                   \
    } while (0)

    STAGE(0, 0);
    __syncthreads();   // drains global_load_lds (vmcnt) + weight stage

    // Thread's q window [qb, qb+4); both float4 reads lane-contiguous.
    const int qb   = 4 * tid;                         // 0..4092
    const int qbl  = qb < 3996 ? qb : 3996;           // main float4 base
    const int qbl2 = (qb + 4) < 3996 ? (qb + 4) : 3996;  // halo float4 base

    float acc[4][8];
    #pragma unroll
    for (int qi = 0; qi < 4; ++qi)
        #pragma unroll
        for (int r = 0; r < 8; ++r) acc[qi][r] = 0.0f;

#define FMA_BODY(A, AN, W0, W1, W2, W3) do {                        \
        const float xl[4] = {(A).x, (A).y, (A).z, (A).w};           \
        const float xh[4] = {(A).y, (A).z, (A).w, (AN)};            \
        const float wa[8] = {(W0).x,(W0).y,(W0).z,(W0).w,           \
                             (W1).x,(W1).y,(W1).z,(W1).w};          \
        const float wb[8] = {(W2).x,(W2).y,(W2).z,(W2).w,           \
                             (W3).x,(W3).y,(W3).z,(W3).w};          \
        _Pragma("unroll")                                           \
        for (int qi = 0; qi < 4; ++qi)                              \
            _Pragma("unroll")                                       \
            for (int r = 0; r < 8; ++r) {                           \
                acc[qi][r] = fmaf(xh[qi], wa[r], acc[qi][r]);       \
                acc[qi][r] = fmaf(xl[qi], wb[r], acc[qi][r]);       \
            }                                                       \
    } while (0)

    #pragma unroll 2
    for (int s = 0; s < NST; ++s) {
        // Issue next stage's async loads BEFORE compute (hide under FMAs).
        if (s < NST - 1) STAGE(s + 1, (s + 1) & 1);

        // Compute the current stage's 4 rows from LDS.
        const float* bufc = xbuf + (s & 1) * (RPS * L_IN);
        #pragma unroll
        for (int r = 0; r < RPS; ++r) {
            const float* row = bufc + r * L_IN;
            float4 a  = *(const float4*)(row + qbl);
            float4 h4 = *(const float4*)(row + qbl2);
            // halo x[qb+4] = h4.x when qb+4 <= 3996; for qb = 3996 the halo
            // feeds only q = 3999 (invalid, lands in slice pad) -> any value ok.
            const float4* wr = (const float4*)(wlds + (s * RPS + r) * KSZ);
            float4 w0 = wr[0], w1 = wr[1], w2 = wr[2], w3 = wr[3];
            FMA_BODY(a, h4.x, w0, w1, w2, w3);
        }

        __syncthreads();   // drains async loads; buf swap safe
    }

    // Epilogue: coalesced partial store. Thread's 32 consecutive floats
    // start at 8*qb; invalid q (>3998, incl. tail threads) lands in the
    // slice pad [31992, 32768) which the reduce kernel never reads.
    float* op = ws + (size_t)(cx * 16 + b) * LOUT_PAD + (size_t)8 * qb;
    #pragma unroll
    for (int qi = 0; qi < 4; ++qi) {
        float4 lo = {acc[qi][0], acc[qi][1], acc[qi][2], acc[qi][3]};
        float4 hi = {acc[qi][4], acc[qi][5], acc[qi][6], acc[qi][7]};
        ((float4*)(op + 8 * qi))[0] = lo;
        ((float4*)(op + 8 * qi))[1] = hi;
    }
#undef FMA_BODY
#undef STAGE
}

// ---------------------------------------------------------------------------
// Reduce kernel (R3-proven): out[b][t] = sum_c ws[c*16+b][t].
// Grid (32, 16) x 256 threads; 16 coalesced float4 addends per thread.
// ---------------------------------------------------------------------------
__global__ __launch_bounds__(256, 8)
void dereverb_reduce(const float* __restrict__ ws, float* __restrict__ out)
{
    const int b  = blockIdx.y;
    const int t4 = blockIdx.x * 256 + threadIdx.x;
    if (t4 >= LOUT / 4) return;

    const float4* p = (const float4*)(ws + (size_t)b * LOUT_PAD) + t4;
    float4 s = {0.0f, 0.0f, 0.0f, 0.0f};
    #pragma unroll
    for (int c = 0; c < NCH; ++c) {
        float4 v = *p;
        s.x += v.x; s.y += v.y; s.z += v.z; s.w += v.w;
        p += (size_t)16 * LOUT_PAD / 4;
    }
    ((float4*)(out + (size_t)b * LOUT))[t4] = s;
}

// ---------------------------------------------------------------------------
// Fallback (ws too small): R0 single-kernel, 195 us known-good.
// ---------------------------------------------------------------------------
#define QPB 256
#define RST 1088
__global__ __launch_bounds__(1024, 4)
void dereverb_fallback(const float* __restrict__ x,
                       const float* __restrict__ t60s,
                       const float* __restrict__ kw,
                       float* __restrict__ out)
{
    __shared__ float lds[8 * RST];

    const int b    = blockIdx.y;
    const int q0   = blockIdx.x * QPB;
    const int tid  = threadIdx.x;
    const int lane = tid & 63;
    const int wave = tid >> 6;

    float t60 = t60s[b & 7];
    int kidx = (int)rintf(t60 * 100.0f) - 10;
    kidx = __builtin_amdgcn_readfirstlane(kidx);
    const float4* wsrc = (const float4*)(kw + (size_t)kidx * (CIN * KSZ));

    ((float4*)lds)[tid]        = wsrc[tid];
    ((float4*)lds)[tid + 1024] = wsrc[tid + 1024];
    __syncthreads();

    const int qb  = q0 + 4 * lane;
    const int qbl = qb < 3996 ? qb : 3996;
    const int qan = (qb + 4) < NQ ? (qb + 4) : NQ;

    const float* xr = x + ((size_t)b * CIN + wave * 32) * L_IN;
    const float* xp = xr + qbl;
    const float* xq = xr + qan;
    const float4* wl = (const float4*)(lds + wave * 32 * KSZ);

    float acc[4][8];
    #pragma unroll
    for (int qi = 0; qi < 4; ++qi)
        #pragma unroll
        for (int r = 0; r < 8; ++r) acc[qi][r] = 0.0f;

    #pragma unroll 4
    for (int ci = 0; ci < 32; ++ci) {
        float4 a  = *(const float4*)xp;
        float  an = *xq;
        xp += L_IN;
        xq += L_IN;

        float4 wv[4];
        wv[0] = wl[0]; wv[1] = wl[1]; wv[2] = wl[2]; wv[3] = wl[3];
        wl += 4;
        const float* wf = (const float*)wv;

        const float x0v[4] = {a.x, a.y, a.z, a.w};
        const float x1v[4] = {a.y, a.z, a.w, an};
        #pragma unroll
        for (int qi = 0; qi < 4; ++qi)
            #pragma unroll
            for (int r = 0; r < 8; ++r) {
                acc[qi][r] = fmaf(x1v[qi], wf[r],     acc[qi][r]);
                acc[qi][r] = fmaf(x0v[qi], wf[r + 8], acc[qi][r]);
            }
    }

    #pragma unroll
    for (int qi = 0; qi < 4; ++qi)
        if (qb + qi > NQ - 1)
            #pragma unroll
            for (int r = 0; r < 8; ++r) acc[qi][r] = 0.0f;

    const size_t obase = (size_t)b * LOUT + (size_t)q0 * 8;
    #pragma unroll
    for (int p = 0; p < 2; ++p) {
        __syncthreads();
        if (wave >= 8) {
            float* rp = lds + (wave - 8) * RST + lane * 17;
            #pragma unroll
            for (int qih = 0; qih < 2; ++qih)
                #pragma unroll
                for (int r = 0; r < 8; ++r)
                    rp[qih * 8 + r] = acc[2 * p + qih][r];
        }
        __syncthreads();
        if (wave < 8) {
            float* rp = lds + wave * RST + lane * 17;
            #pragma unroll
            for (int qih = 0; qih < 2; ++qih)
                #pragma unroll
                for (int r = 0; r < 8; ++r)
                    rp[qih * 8 + r] += acc[2 * p + qih][r];
        }
        __syncthreads();
        int k = tid >> 4, j = tid & 15;
        int tl = 32 * k + 16 * p + j;
        if (q0 * 8 + tl < LOUT) {
            float s = 0.0f;
            #pragma unroll
            for (int w = 0; w < 8; ++w)
                s += lds[w * RST + k * 17 + j];
            out[obase + tl] = s;
        }
    }
}

extern "C" void kernel_launch(void* const* d_in, const int* in_sizes, int n_in,
                              void* d_out, int out_size, void* d_ws, size_t ws_size,
                              hipStream_t stream) {
    const float* x    = (const float*)d_in[0];   // (16, 512, 4000)
    const float* t60s = (const float*)d_in[1];   // (8,)
    const float* kw   = (const float*)d_in[2];   // (41, 512, 1, 16)
    float* out = (float*)d_out;                  // (16, 1, 31992)

    if (ws_size >= WS_FLOATS * sizeof(float) && d_ws != nullptr) {
        float* ws = (float*)d_ws;
        dim3 g1(NCH, 16);                        // (16 ci-chunks, 16 b) = 256
        dereverb_stage<<<g1, 1024, 0, stream>>>(x, t60s, kw, ws);
        dim3 g2((LOUT / 4 + 255) / 256, 16);     // (32, 16) = 512
        dereverb_reduce<<<g2, 256, 0, stream>>>(ws, out);
    } else {
        dim3 grid((NQ + QPB - 1) / QPB, 16);     // (16, 16)
        dereverb_fallback<<<grid, 1024, 0, stream>>>(x, t60s, kw, out);
    }
}

// Round 7
// 190.825 us; speedup vs baseline: 1.8542x; 1.0814x over previous
//
#include <hip/hip_runtime.h>

#define L_IN   4000
#define CIN    512
#define KSZ    16
#define LOUT   31992   // 8 * 3999
#define NQ     3999    // valid q: 0..3998
#define QPB    256     // q positions per block (4 contiguous per thread)
#define RST    1088    // reduction region stride: 64 lanes * 17 floats

// FINAL ARTIFACT — reverted to the best harness-verified kernel (195.4 us).
// Six structural probes (R1-R6: pipelining/barrier-domains, atomics,
// macro-contiguity, 2x occupancy, coherent LDS-staged sequential streaming
// via global_load_lds) all returned null or regressed: the mixed
// read-dominant stream runs at a pattern-independent ~3.2 TB/s on this op,
// and this kernel's ~42 us sits on that wall. The remaining ~153 us of the
// bench is the harness's poison-fill floor (86% of HBM peak).
//
// Block = (b, 256-q tile), 1024 threads = 16 waves; wave w owns ci [w*32, +32).
// Thread: 4 CONTIGUOUS q's (qb = q0 + 4*lane) -> per (wave,ci) the x-load is
// one 1 KB contiguous float4 burst; halo x[q+4] from a stride-4 dword load
// (L1-hit). Weights staged once to LDS, wave-uniform ds_read_b128 broadcast.
// 16-wave reduction: two qi-half passes, per-lane 17-padded chunks (skewed,
// bank-balanced); 34 KB LDS total, unioned with the 32 KB weight stage.
__global__ __launch_bounds__(1024, 4)
void dereverb_kernel(const float* __restrict__ x,
                     const float* __restrict__ t60s,
                     const float* __restrict__ kw,
                     float* __restrict__ out)
{
    __shared__ float lds[8 * RST];   // 34 KB

    const int b    = blockIdx.y;
    const int q0   = blockIdx.x * QPB;
    const int tid  = threadIdx.x;
    const int lane = tid & 63;
    const int wave = tid >> 6;

    // Per-sample kernel index (uniform): jnp.round = RNE = rintf.
    float t60 = t60s[b & 7];
    int kidx = (int)rintf(t60 * 100.0f) - 10;
    kidx = __builtin_amdgcn_readfirstlane(kidx);
    const float4* wsrc = (const float4*)(kw + (size_t)kidx * (CIN * KSZ));

    // Stage all 512x16 weights: 2048 float4 / 1024 threads = 2 each, coalesced.
    ((float4*)lds)[tid]        = wsrc[tid];
    ((float4*)lds)[tid + 1024] = wsrc[tid + 1024];
    __syncthreads();

    // Lane's q base; clamp keeps all loads inside the current row:
    //  - float4 at qbl: qbl <= 3996 -> reads x[3996..3999], in-bounds
    //  - halo dword at qan = min(qb+4, 3999), in-bounds
    // Lanes/q's past 3998 produce garbage that is zeroed before reduction.
    const int qb  = q0 + 4 * lane;
    const int qbl = qb < 3996 ? qb : 3996;          // multiple of 4 -> 16B aligned
    const int qan = (qb + 4) < NQ ? (qb + 4) : NQ;  // min(qb+4, 3999)

    const float* xr = x + ((size_t)b * CIN + wave * 32) * L_IN;
    const float* xp = xr + qbl;
    const float* xq = xr + qan;

    const float4* wl = (const float4*)(lds + wave * 32 * KSZ);

    float acc[4][8];
    #pragma unroll
    for (int qi = 0; qi < 4; ++qi)
        #pragma unroll
        for (int r = 0; r < 8; ++r) acc[qi][r] = 0.0f;

    #pragma unroll 4
    for (int ci = 0; ci < 32; ++ci) {
        float4 a  = *(const float4*)xp;   // x[q .. q+3], 1 KB/wave contiguous
        float  an = *xq;                  // x[q+4] halo (cache-hit)
        xp += L_IN;
        xq += L_IN;

        float4 wv[4];
        wv[0] = wl[0];                    // wave-uniform ds_read_b128 -> broadcast
        wv[1] = wl[1];
        wv[2] = wl[2];
        wv[3] = wl[3];
        wl += 4;
        const float* wf = (const float*)wv;

        const float x0v[4] = {a.x, a.y, a.z, a.w};
        const float x1v[4] = {a.y, a.z, a.w, an};
        #pragma unroll
        for (int qi = 0; qi < 4; ++qi)
            #pragma unroll
            for (int r = 0; r < 8; ++r) {
                acc[qi][r] = fmaf(x1v[qi], wf[r],     acc[qi][r]);
                acc[qi][r] = fmaf(x0v[qi], wf[r + 8], acc[qi][r]);
            }
    }

    // Zero contributions from invalid q (> 3998) / clamped lanes.
    #pragma unroll
    for (int qi = 0; qi < 4; ++qi)
        if (qb + qi > NQ - 1)
            #pragma unroll
            for (int r = 0; r < 8; ++r) acc[qi][r] = 0.0f;

    // 16-wave reduction in two passes over qi-halves (qi = 2p+qih).
    // Region w layout: addr = w*RST + lane*17 + qih*8 + r  (17-padded chunk:
    // b128 stores are perfectly bank-balanced; epilogue reads <=3-way).
    const size_t obase = (size_t)b * LOUT + (size_t)q0 * 8;
    #pragma unroll
    for (int p = 0; p < 2; ++p) {
        __syncthreads();                 // weights / previous pass reads done
        if (wave >= 8) {                 // waves 8..15 store region (wave-8)
            float* rp = lds + (wave - 8) * RST + lane * 17;
            #pragma unroll
            for (int qih = 0; qih < 2; ++qih)
                #pragma unroll
                for (int r = 0; r < 8; ++r)
                    rp[qih * 8 + r] = acc[2 * p + qih][r];
        }
        __syncthreads();
        if (wave < 8) {                  // waves 0..7 fold into region wave
            float* rp = lds + wave * RST + lane * 17;
            #pragma unroll
            for (int qih = 0; qih < 2; ++qih)
                #pragma unroll
                for (int r = 0; r < 8; ++r)
                    rp[qih * 8 + r] += acc[2 * p + qih][r];
        }
        __syncthreads();
        // Pass p covers, per compute-lane k, the 16 outputs t_local =
        // 32k + 16p + j  (j = qih*8 + r). 1024 outputs/pass, one per thread.
        int k = tid >> 4, j = tid & 15;
        int tl = 32 * k + 16 * p + j;
        if (q0 * 8 + tl < LOUT) {        // only the last q-tile trims
            float s = 0.0f;
            #pragma unroll
            for (int w = 0; w < 8; ++w)
                s += lds[w * RST + k * 17 + j];
            out[obase + tl] = s;
        }
    }
}

extern "C" void kernel_launch(void* const* d_in, const int* in_sizes, int n_in,
                              void* d_out, int out_size, void* d_ws, size_t ws_size,
                              hipStream_t stream) {
    const float* x    = (const float*)d_in[0];   // (16, 512, 4000)
    const float* t60s = (const float*)d_in[1];   // (8,)
    const float* kw   = (const float*)d_in[2];   // (41, 512, 1, 16)
    float* out = (float*)d_out;                  // (16, 1, 31992)

    dim3 grid((NQ + QPB - 1) / QPB, 16);         // (16, 16)
    dereverb_kernel<<<grid, 1024, 0, stream>>>(x, t60s, kw, out);
}